// Round 2
// baseline (194.160 us; speedup 1.0000x reference)
//
#include <hip/hip_runtime.h>
#include <hip/hip_bf16.h>

// TT embedding: vocab 65536, dim 1024, rank 16.
// out[v,d] = sum_{r1..r4} c0[0,i0,r1] c1[r1,i1,r2] c2[r2,i2,r3] c3[r3,i3,r4] c4[r4,i4,0]
//   i0=v>>11, i1=(v>>6)&31, i2=(v>>1)&31, i3=(v&1)*16+(d>>6), i4=d&63
//
// Block = 256 threads handles G=16 tokens. Grid = 1024 blocks = 4 blocks/CU
// co-resident (VGPR<=128 via launch_bounds, LDS 22.5KB).
// Stage 1/2: thread=(g, r)      -> 256/256 threads busy on 16x16 contractions
// Stage 3:   thread=(g, d1)     -> 16 accumulators in regs, float4 c3 loads,
//                                  4x ds_write_b128 into pad-20 w4 rows
// Stage 4:   thread=(d1, i4/4)  -> c4 column slice in 64 VGPRs reused over 16
//                                  tokens; one coalesced float4 store each.

#define G 16

__global__ __launch_bounds__(256, 4) void tt_embed_kernel(
    const float* __restrict__ c0,   // 32*16
    const float* __restrict__ c1,   // 16*32*16
    const float* __restrict__ c2,   // 16*32*16
    const float* __restrict__ c3,   // 16*32*16
    const float* __restrict__ c4,   // 16*64
    const int*   __restrict__ idx,  // n_tokens
    float*       __restrict__ out,  // n_tokens x 1024
    int n_tokens)
{
    const int t = threadIdx.x;
    const int base = blockIdx.x * G;

    __shared__ float w2[G][16];
    __shared__ float w3[G][16];
    __shared__ float w4[G][16][20];   // row pad 20 floats: 8 bank-bases, 16B-aligned rows

    // ---- Stage 1: w2[g][r2] = sum_r1 c0[i0,r1] * c1[r1,i1,r2]
    {
        const int g = t >> 4, r2 = t & 15;
        const int token = base + g;
        const int v = (token < n_tokens) ? idx[token] : 0;
        const int i0 = (v >> 11) & 31;
        const int i1 = (v >> 6) & 31;
        float acc = 0.f;
        #pragma unroll
        for (int r1 = 0; r1 < 16; ++r1)
            acc = fmaf(c0[i0 * 16 + r1], c1[(r1 * 32 + i1) * 16 + r2], acc);
        w2[g][r2] = acc;
    }
    __syncthreads();

    // ---- Stage 2: w3[g][r3] = sum_r2 w2[g][r2] * c2[r2,i2,r3]
    {
        const int g = t >> 4, r3 = t & 15;
        const int token = base + g;
        const int v = (token < n_tokens) ? idx[token] : 0;
        const int i2 = (v >> 1) & 31;
        float acc = 0.f;
        #pragma unroll
        for (int r2 = 0; r2 < 16; ++r2)
            acc = fmaf(w2[g][r2], c2[(r2 * 32 + i2) * 16 + r3], acc);
        w3[g][r3] = acc;
    }
    __syncthreads();

    // ---- Stage 3: w4[g][d1][r4] = sum_r3 w3[g][r3] * c3[r3, i3, r4]
    {
        const int g = t >> 4, d1 = t & 15;
        const int token = base + g;
        const int v = (token < n_tokens) ? idx[token] : 0;
        const int i3 = ((v & 1) << 4) + d1;
        float4 a0 = {0,0,0,0}, a1 = {0,0,0,0}, a2 = {0,0,0,0}, a3 = {0,0,0,0};
        #pragma unroll
        for (int r3 = 0; r3 < 16; ++r3) {
            const float w = w3[g][r3];
            const float4* row = (const float4*)(c3 + (r3 * 32 + i3) * 16);
            float4 b0 = row[0], b1 = row[1], b2 = row[2], b3 = row[3];
            a0.x = fmaf(w, b0.x, a0.x); a0.y = fmaf(w, b0.y, a0.y);
            a0.z = fmaf(w, b0.z, a0.z); a0.w = fmaf(w, b0.w, a0.w);
            a1.x = fmaf(w, b1.x, a1.x); a1.y = fmaf(w, b1.y, a1.y);
            a1.z = fmaf(w, b1.z, a1.z); a1.w = fmaf(w, b1.w, a1.w);
            a2.x = fmaf(w, b2.x, a2.x); a2.y = fmaf(w, b2.y, a2.y);
            a2.z = fmaf(w, b2.z, a2.z); a2.w = fmaf(w, b2.w, a2.w);
            a3.x = fmaf(w, b3.x, a3.x); a3.y = fmaf(w, b3.y, a3.y);
            a3.z = fmaf(w, b3.z, a3.z); a3.w = fmaf(w, b3.w, a3.w);
        }
        float4* wrow = (float4*)&w4[g][d1][0];
        wrow[0] = a0; wrow[1] = a1; wrow[2] = a2; wrow[3] = a3;
    }
    __syncthreads();

    // ---- Stage 4: out[token, d] = sum_r4 w4[g][d>>6][r4] * c4[r4, d&63]
    {
        const int d1  = t >> 4;
        const int i4b = (t & 15) << 2;

        float4 c4v[16];
        #pragma unroll
        for (int r4 = 0; r4 < 16; ++r4)
            c4v[r4] = *(const float4*)(c4 + (r4 << 6) + i4b);

        const int gmax = (n_tokens - base < G) ? (n_tokens - base) : G;
        for (int g = 0; g < gmax; ++g) {
            const float* wr = &w4[g][d1][0];
            float wv[16];
            #pragma unroll
            for (int r4 = 0; r4 < 16; ++r4) wv[r4] = wr[r4];

            float4 acc = {0,0,0,0};
            #pragma unroll
            for (int r4 = 0; r4 < 16; ++r4) {
                acc.x = fmaf(wv[r4], c4v[r4].x, acc.x);
                acc.y = fmaf(wv[r4], c4v[r4].y, acc.y);
                acc.z = fmaf(wv[r4], c4v[r4].z, acc.z);
                acc.w = fmaf(wv[r4], c4v[r4].w, acc.w);
            }
            *(float4*)(out + (size_t)(base + g) * 1024 + (t << 2)) = acc;
        }
    }
}

extern "C" void kernel_launch(void* const* d_in, const int* in_sizes, int n_in,
                              void* d_out, int out_size, void* d_ws, size_t ws_size,
                              hipStream_t stream) {
    const float* c0  = (const float*)d_in[0];
    const float* c1  = (const float*)d_in[1];
    const float* c2  = (const float*)d_in[2];
    const float* c3  = (const float*)d_in[3];
    const float* c4  = (const float*)d_in[4];
    const int*   idx = (const int*)d_in[5];
    float* out = (float*)d_out;

    const int n_tokens = in_sizes[5];         // 8 * 2048 = 16384
    const int grid = (n_tokens + G - 1) / G;  // 1024
    tt_embed_kernel<<<grid, 256, 0, stream>>>(c0, c1, c2, c3, c4, idx, out, n_tokens);
}

// Round 3
// 47.040 us; speedup vs baseline: 4.1275x; 4.1275x over previous
//
#include <hip/hip_runtime.h>
#include <hip/hip_bf16.h>

// TT embedding: vocab 65536, dim 1024, rank 16.
// out[v,d] = sum_{r1..r4} c0[0,i0,r1] c1[r1,i1,r2] c2[r2,i2,r3] c3[r3,i3,r4] c4[r4,i4,0]
//   i0=v>>11, i1=(v>>6)&31, i2=(v>>1)&31, i3=(v&1)*16+(d>>6), i4=d&63
//
// Block = 256 threads handles G=16 tokens; grid = 1024 blocks.
// R2 lesson: __launch_bounds__(256,4) capped VGPRs at 64 -> c4v[16] (64 regs)
// spilled to scratch -> 443 MB of HBM scratch reads, 194 us. Fix: no min-wave
// clamp (need ~100 VGPRs live in stage 4) + no-unroll on the g-loop.

#define G 16

__global__ __launch_bounds__(256) void tt_embed_kernel(
    const float* __restrict__ c0,   // 32*16
    const float* __restrict__ c1,   // 16*32*16
    const float* __restrict__ c2,   // 16*32*16
    const float* __restrict__ c3,   // 16*32*16
    const float* __restrict__ c4,   // 16*64
    const int*   __restrict__ idx,  // n_tokens
    float*       __restrict__ out,  // n_tokens x 1024
    int n_tokens)
{
    const int t = threadIdx.x;
    const int base = blockIdx.x * G;

    __shared__ float w2[G][16];
    __shared__ float w3[G][16];
    __shared__ float w4[G][16][20];   // pad to 20 floats/row; rows 16B-aligned

    // ---- Stage 1: w2[g][r2] = sum_r1 c0[i0,r1] * c1[r1,i1,r2]
    {
        const int g = t >> 4, r2 = t & 15;
        const int token = base + g;
        const int v = (token < n_tokens) ? idx[token] : 0;
        const int i0 = (v >> 11) & 31;
        const int i1 = (v >> 6) & 31;
        float acc = 0.f;
        #pragma unroll
        for (int r1 = 0; r1 < 16; ++r1)
            acc = fmaf(c0[i0 * 16 + r1], c1[(r1 * 32 + i1) * 16 + r2], acc);
        w2[g][r2] = acc;
    }
    __syncthreads();

    // ---- Stage 2: w3[g][r3] = sum_r2 w2[g][r2] * c2[r2,i2,r3]
    {
        const int g = t >> 4, r3 = t & 15;
        const int token = base + g;
        const int v = (token < n_tokens) ? idx[token] : 0;
        const int i2 = (v >> 1) & 31;
        float acc = 0.f;
        #pragma unroll
        for (int r2 = 0; r2 < 16; ++r2)
            acc = fmaf(w2[g][r2], c2[(r2 * 32 + i2) * 16 + r3], acc);
        w3[g][r3] = acc;
    }
    __syncthreads();

    // ---- Stage 3: w4[g][d1][r4] = sum_r3 w3[g][r3] * c3[r3, i3, r4]
    {
        const int g = t >> 4, d1 = t & 15;
        const int token = base + g;
        const int v = (token < n_tokens) ? idx[token] : 0;
        const int i3 = ((v & 1) << 4) + d1;
        float4 a0 = {0,0,0,0}, a1 = {0,0,0,0}, a2 = {0,0,0,0}, a3 = {0,0,0,0};
        #pragma unroll
        for (int r3 = 0; r3 < 16; ++r3) {
            const float w = w3[g][r3];
            const float4* row = (const float4*)(c3 + (r3 * 32 + i3) * 16);
            float4 b0 = row[0], b1 = row[1], b2 = row[2], b3 = row[3];
            a0.x = fmaf(w, b0.x, a0.x); a0.y = fmaf(w, b0.y, a0.y);
            a0.z = fmaf(w, b0.z, a0.z); a0.w = fmaf(w, b0.w, a0.w);
            a1.x = fmaf(w, b1.x, a1.x); a1.y = fmaf(w, b1.y, a1.y);
            a1.z = fmaf(w, b1.z, a1.z); a1.w = fmaf(w, b1.w, a1.w);
            a2.x = fmaf(w, b2.x, a2.x); a2.y = fmaf(w, b2.y, a2.y);
            a2.z = fmaf(w, b2.z, a2.z); a2.w = fmaf(w, b2.w, a2.w);
            a3.x = fmaf(w, b3.x, a3.x); a3.y = fmaf(w, b3.y, a3.y);
            a3.z = fmaf(w, b3.z, a3.z); a3.w = fmaf(w, b3.w, a3.w);
        }
        float4* wrow = (float4*)&w4[g][d1][0];
        wrow[0] = a0; wrow[1] = a1; wrow[2] = a2; wrow[3] = a3;
    }
    __syncthreads();

    // ---- Stage 4: out[token, d] = sum_r4 w4[g][d>>6][r4] * c4[r4, d&63]
    {
        const int d1  = t >> 4;          // d>>6 for d = t*4
        const int i4b = (t & 15) << 2;   // d&63 base

        float4 c4v[16];                  // 64 VGPRs, reused across all 16 tokens
        #pragma unroll
        for (int r4 = 0; r4 < 16; ++r4)
            c4v[r4] = *(const float4*)(c4 + (r4 << 6) + i4b);

        float* outp = out + (size_t)base * 1024 + (t << 2);
        #pragma unroll 1                 // keep ONE token's live range at a time
        for (int g = 0; g < G; ++g) {
            const float* wr = &w4[g][d1][0];
            float4 acc = {0,0,0,0};
            #pragma unroll
            for (int r4 = 0; r4 < 16; ++r4) {
                const float wv = wr[r4];
                acc.x = fmaf(wv, c4v[r4].x, acc.x);
                acc.y = fmaf(wv, c4v[r4].y, acc.y);
                acc.z = fmaf(wv, c4v[r4].z, acc.z);
                acc.w = fmaf(wv, c4v[r4].w, acc.w);
            }
            *(float4*)(outp + (size_t)g * 1024) = acc;
        }
    }
}

extern "C" void kernel_launch(void* const* d_in, const int* in_sizes, int n_in,
                              void* d_out, int out_size, void* d_ws, size_t ws_size,
                              hipStream_t stream) {
    const float* c0  = (const float*)d_in[0];
    const float* c1  = (const float*)d_in[1];
    const float* c2  = (const float*)d_in[2];
    const float* c3  = (const float*)d_in[3];
    const float* c4  = (const float*)d_in[4];
    const int*   idx = (const int*)d_in[5];
    float* out = (float*)d_out;

    const int n_tokens = in_sizes[5];         // 8 * 2048 = 16384
    const int grid = (n_tokens + G - 1) / G;  // 1024
    tt_embed_kernel<<<grid, 256, 0, stream>>>(c0, c1, c2, c3, c4, idx, out, n_tokens);
}